// Round 1
// baseline (651.933 us; speedup 1.0000x reference)
//
#include <hip/hip_runtime.h>
#include <hip/hip_bf16.h>

using bf16_t = __hip_bfloat16;
typedef __attribute__((ext_vector_type(8))) __bf16 bfrag;   // 8 bf16 = 4 VGPR (MFMA A/B operand)
typedef __attribute__((ext_vector_type(4))) float f32x4;    // MFMA C/D operand

__device__ __forceinline__ void gload_lds16(const void* g, void* l) {
  // async global->LDS, 16B/lane; LDS dest = wave-uniform base + lane*16
  __builtin_amdgcn_global_load_lds((const __attribute__((address_space(1))) void*)g,
                                   (__attribute__((address_space(3))) void*)l, 16, 0, 0);
}

// ---------- weight transpose + f32->bf16 convert: in[K][N] f32 -> out[N][K] bf16 ----------
__global__ __launch_bounds__(256) void transpose_cvt(const float* __restrict__ in,
    bf16_t* __restrict__ out, int K, int N) {
  __shared__ float t[32][33];
  const int n0 = blockIdx.x * 32, k0 = blockIdx.y * 32;
  const int tx = threadIdx.x & 31, ty = threadIdx.x >> 5;   // 32 x 8
#pragma unroll
  for (int i = 0; i < 4; ++i)
    t[ty + i * 8][tx] = in[(size_t)(k0 + ty + i * 8) * N + n0 + tx];
  __syncthreads();
#pragma unroll
  for (int i = 0; i < 4; ++i)
    out[(size_t)(n0 + ty + i * 8) * K + k0 + tx] = bf16_t(t[tx][ty + i * 8]);
}

// ---------- LayerNorm: x f32 [2048][2048] -> h bf16 ----------
__global__ __launch_bounds__(256) void ln_kernel(const float* __restrict__ x,
    const float* __restrict__ sc, const float* __restrict__ of, bf16_t* __restrict__ h) {
  __shared__ float red[8];
  const int n = blockIdx.x, tid = threadIdx.x;
  const float* xr = x + (size_t)n * 2048;
  float4 a = ((const float4*)xr)[tid * 2];
  float4 b = ((const float4*)xr)[tid * 2 + 1];
  float s = a.x + a.y + a.z + a.w + b.x + b.y + b.z + b.w;
  float q = a.x * a.x + a.y * a.y + a.z * a.z + a.w * a.w +
            b.x * b.x + b.y * b.y + b.z * b.z + b.w * b.w;
#pragma unroll
  for (int m = 32; m; m >>= 1) { s += __shfl_xor(s, m); q += __shfl_xor(q, m); }
  if ((tid & 63) == 0) { red[(tid >> 6) * 2] = s; red[(tid >> 6) * 2 + 1] = q; }
  __syncthreads();
  s = red[0] + red[2] + red[4] + red[6];
  q = red[1] + red[3] + red[5] + red[7];
  const float mu = s * (1.f / 2048.f);
  const float inv = rsqrtf(q * (1.f / 2048.f) - mu * mu + 1e-5f);
  const int base = tid * 8;
  float v[8] = {a.x, a.y, a.z, a.w, b.x, b.y, b.z, b.w};
  bf16_t* hr = h + (size_t)n * 2048 + base;
#pragma unroll
  for (int j = 0; j < 8; ++j) hr[j] = bf16_t((v[j] - mu) * inv * sc[base + j] + of[base + j]);
}

// ---------- GEMM: C[M][N] = A[M][K](bf16) * BT[N][K](bf16)^T, f32 accum ----------
// EPI bits: 1=+bias[col], 2=gelu(tanh), 4=+Cin[row][col], 8=store bf16 (else f32)
template <int EPI>
__global__ __launch_bounds__(256) void gemm_bt(
    const bf16_t* __restrict__ A, const bf16_t* __restrict__ BT,
    const float* __restrict__ bias, const float* __restrict__ Cin,
    float* __restrict__ Cf, bf16_t* __restrict__ Cb, int M, int N, int K) {
  __shared__ alignas(16) bf16_t As[128 * 32];   // [row][k] 8KB
  __shared__ alignas(16) bf16_t Bs[128 * 32];   // [col][k] 8KB
  const int tid = threadIdx.x;
  const int wid = tid >> 6, lane = tid & 63;
  const int lc = lane & 15, lg = lane >> 4;
  const int bm = blockIdx.y * 128, bn = blockIdx.x * 128;
  const int wr = (wid >> 1) * 64, wc = (wid & 1) * 64;      // wave 64x64 sub-tile
  f32x4 acc[4][4] = {};
  for (int k0 = 0; k0 < K; k0 += 32) {
    __syncthreads();  // previous tile's reads done before overwrite
#pragma unroll
    for (int i = 0; i < 2; ++i) {
      const int e = i * 2048 + tid * 8;            // element index in 128x32 tile
      const int r = e >> 5, c = e & 31;
      gload_lds16(A + (size_t)(bm + r) * K + k0 + c, (char*)As + i * 4096 + wid * 1024);
      gload_lds16(BT + (size_t)(bn + r) * K + k0 + c, (char*)Bs + i * 4096 + wid * 1024);
    }
    __syncthreads();  // drains vmcnt
    bfrag af[4], bfv[4];
#pragma unroll
    for (int m = 0; m < 4; ++m) af[m] = *(const bfrag*)&As[(wr + m * 16 + lc) * 32 + lg * 8];
#pragma unroll
    for (int n = 0; n < 4; ++n) bfv[n] = *(const bfrag*)&Bs[(wc + n * 16 + lc) * 32 + lg * 8];
#pragma unroll
    for (int m = 0; m < 4; ++m)
#pragma unroll
      for (int n = 0; n < 4; ++n)
        acc[m][n] = __builtin_amdgcn_mfma_f32_16x16x32_bf16(af[m], bfv[n], acc[m][n], 0, 0, 0);
  }
  const int row0 = bm + wr + lg * 4;
  const int col0 = bn + wc + lc;
#pragma unroll
  for (int m = 0; m < 4; ++m) {
#pragma unroll
    for (int n = 0; n < 4; ++n) {
      const int col = col0 + n * 16;
      float bv = (EPI & 1) ? bias[col] : 0.f;
#pragma unroll
      for (int i = 0; i < 4; ++i) {
        const int row = row0 + m * 16 + i;
        float v = acc[m][n][i];
        if (EPI & 1) v += bv;
        if (EPI & 2) v = 0.5f * v * (1.f + tanhf(0.7978845608028654f * (v + 0.044715f * v * v * v)));
        if (EPI & 4) v += Cin[(size_t)row * N + col];
        if (EPI & 8) Cb[(size_t)row * N + col] = bf16_t(v);
        else         Cf[(size_t)row * N + col] = v;
      }
    }
  }
}

// ---------- RoPE + head split: qkv bf16 [2048][6144] -> qh/kh [16][2048][128], vT [16][128][2048] ----------
__global__ __launch_bounds__(128) void rope_kernel(const bf16_t* __restrict__ qkv,
    bf16_t* __restrict__ qh, bf16_t* __restrict__ kh, bf16_t* __restrict__ vT) {
  const int n = blockIdx.x, hh = blockIdx.y;
  const int d = threadIdx.x;
  const int mp = hh >> 2, hi = hh & 3;
  const bf16_t* row = qkv + (size_t)n * 6144 + mp * 1536 + hi * 128;  // [q|v|k] each 512 per mp
  float q = __bfloat162float(row[d]);
  float k = __bfloat162float(row[1024 + d]);
  if (d < 64) {  // wave-uniform branch (wave 0 = lanes 0..63)
    const float ang = (float)n * powf(10000.f, -(float)(d & ~1) / 64.f);
    const float sn = sinf(ang), cs = cosf(ang);
    const float qp = __shfl_xor(q, 1), kp = __shfl_xor(k, 1);
    if (d & 1) { q = q * cs + qp * sn; k = k * cs + kp * sn; }
    else       { q = q * cs - qp * sn; k = k * cs - kp * sn; }
  }
  qh[((size_t)hh * 2048 + n) * 128 + d] = bf16_t(q * 0.08838834764831845f); // 1/sqrt(128)
  kh[((size_t)hh * 2048 + n) * 128 + d] = bf16_t(k);
  vT[((size_t)hh * 128 + d) * 2048 + n] = row[512 + d];
}

// ---------- causal flash attention: 1 block = (head, 64 q-rows), 4 waves x 16 rows ----------
__global__ __launch_bounds__(256) void attn_kernel(const bf16_t* __restrict__ qh,
    const bf16_t* __restrict__ kh, const bf16_t* __restrict__ vT, bf16_t* __restrict__ av) {
  __shared__ alignas(16) bf16_t Ks[64 * 128];   // [kv][d] 16KB
  __shared__ alignas(16) bf16_t Vs[128 * 64];   // [d][kv] 16KB
  __shared__ alignas(16) bf16_t Ps[4][16 * 64]; // per-wave P 8KB
  const int qt = blockIdx.x, h = blockIdx.y;
  const int tid = threadIdx.x, wid = tid >> 6, lane = tid & 63;
  const int lc = lane & 15, lg = lane >> 4;
  const int qr = qt * 64 + wid * 16;
  const bf16_t* Qb = qh + ((size_t)h * 2048 + qr) * 128;
  bfrag qf[4];
#pragma unroll
  for (int ks = 0; ks < 4; ++ks)
    qf[ks] = *(const bfrag*)&Qb[lc * 128 + ks * 32 + lg * 8];
  f32x4 O[8] = {};
  float mr[4] = {-1e30f, -1e30f, -1e30f, -1e30f};
  float lsum[4] = {0.f, 0.f, 0.f, 0.f};
  for (int kt = 0; kt <= qt; ++kt) {
    const int kv0 = kt * 64;
    __syncthreads();
#pragma unroll
    for (int i = 0; i < 4; ++i) {
      const int e = i * 2048 + tid * 8;
      gload_lds16(kh + ((size_t)h * 2048 + kv0 + (e >> 7)) * 128 + (e & 127),
                  (char*)Ks + i * 4096 + wid * 1024);
      gload_lds16(vT + ((size_t)h * 128 + (e >> 6)) * 2048 + kv0 + (e & 63),
                  (char*)Vs + i * 4096 + wid * 1024);
    }
    __syncthreads();
    f32x4 s[4];
#pragma unroll
    for (int c = 0; c < 4; ++c) {
      f32x4 a = {};
#pragma unroll
      for (int ks = 0; ks < 4; ++ks) {
        bfrag kf = *(const bfrag*)&Ks[(c * 16 + lc) * 128 + ks * 32 + lg * 8];
        a = __builtin_amdgcn_mfma_f32_16x16x32_bf16(qf[ks], kf, a, 0, 0, 0);
      }
      s[c] = a;
    }
    if (kv0 + 63 > qr) {  // diagonal tile: causal mask, replace like jnp.where
#pragma unroll
      for (int c = 0; c < 4; ++c)
#pragma unroll
        for (int i = 0; i < 4; ++i)
          if (kv0 + c * 16 + lc > qr + lg * 4 + i) s[c][i] = -1e10f;
    }
    float pm[4];
#pragma unroll
    for (int i = 0; i < 4; ++i)
      pm[i] = fmaxf(fmaxf(s[0][i], s[1][i]), fmaxf(s[2][i], s[3][i]));
#pragma unroll
    for (int m = 1; m < 16; m <<= 1)
#pragma unroll
      for (int i = 0; i < 4; ++i) pm[i] = fmaxf(pm[i], __shfl_xor(pm[i], m));
    float al[4], rs[4];
#pragma unroll
    for (int i = 0; i < 4; ++i) {
      const float mn = fmaxf(mr[i], pm[i]);
      al[i] = __expf(mr[i] - mn);
      mr[i] = mn;
      rs[i] = 0.f;
    }
#pragma unroll
    for (int c = 0; c < 4; ++c)
#pragma unroll
      for (int i = 0; i < 4; ++i) {
        const float p = __expf(s[c][i] - mr[i]);
        s[c][i] = p; rs[i] += p;
      }
#pragma unroll
    for (int m = 1; m < 16; m <<= 1)
#pragma unroll
      for (int i = 0; i < 4; ++i) rs[i] += __shfl_xor(rs[i], m);
#pragma unroll
    for (int i = 0; i < 4; ++i) lsum[i] = lsum[i] * al[i] + rs[i];
#pragma unroll
    for (int n = 0; n < 8; ++n)
#pragma unroll
      for (int i = 0; i < 4; ++i) O[n][i] *= al[i];
    // P (C-layout) -> LDS -> A-operand layout
#pragma unroll
    for (int c = 0; c < 4; ++c)
#pragma unroll
      for (int i = 0; i < 4; ++i)
        Ps[wid][(lg * 4 + i) * 64 + c * 16 + lc] = bf16_t(s[c][i]);
#pragma unroll
    for (int k2 = 0; k2 < 2; ++k2) {
      bfrag pf = *(const bfrag*)&Ps[wid][lc * 64 + k2 * 32 + lg * 8];
#pragma unroll
      for (int n = 0; n < 8; ++n) {
        bfrag vf = *(const bfrag*)&Vs[(n * 16 + lc) * 64 + k2 * 32 + lg * 8];
        O[n] = __builtin_amdgcn_mfma_f32_16x16x32_bf16(pf, vf, O[n], 0, 0, 0);
      }
    }
  }
#pragma unroll
  for (int n = 0; n < 8; ++n)
#pragma unroll
    for (int i = 0; i < 4; ++i)
      av[(size_t)(qr + lg * 4 + i) * 2048 + h * 128 + n * 16 + lc] = bf16_t(O[n][i] / lsum[i]);
}

extern "C" void kernel_launch(void* const* d_in, const int* in_sizes, int n_in,
                              void* d_out, int out_size, void* d_ws, size_t ws_size,
                              hipStream_t stream) {
  const float* x        = (const float*)d_in[0];
  const float* ln_scale = (const float*)d_in[1];
  const float* ln_offset= (const float*)d_in[2];
  const float* w_qkv    = (const float*)d_in[3];   // [2048][6144]
  const float* w_ao     = (const float*)d_in[4];   // [2048][2048]
  const float* w_ff_in  = (const float*)d_in[5];   // [2048][8192]
  const float* b_ff_in  = (const float*)d_in[6];   // [8192]
  const float* w_ff_out = (const float*)d_in[7];   // [8192][2048]
  const float* b_ff_out = (const float*)d_in[8];   // [2048]
  float* out = (float*)d_out;

  char* ws = (char*)d_ws;
  bf16_t* wqkvT   = (bf16_t*)(ws);                  // [6144][2048] 25.2MB
  bf16_t* waoT    = (bf16_t*)(ws + 25165824);       // [2048][2048] 8.4MB
  bf16_t* wffinT  = (bf16_t*)(ws + 33554432);       // [8192][2048] 33.6MB
  bf16_t* wffoutT = (bf16_t*)(ws + 67108864);       // [2048][8192] 33.6MB
  bf16_t* h       = (bf16_t*)(ws + 100663296);      // [2048][2048] 8.4MB
  bf16_t* qhb     = (bf16_t*)(ws + 109051904);      // [16][2048][128]
  bf16_t* khb     = (bf16_t*)(ws + 117440512);      // [16][2048][128]
  bf16_t* vTb     = (bf16_t*)(ws + 125829120);      // [16][128][2048]
  bf16_t* avb     = (bf16_t*)(ws + 134217728);      // [2048][2048]
  bf16_t* qkvb    = (bf16_t*)(ws + 142606336);      // [2048][6144] (reused as ff1 [2048][8192])
  bf16_t* ff1b    = qkvb;

  dim3 b256(256);
  transpose_cvt<<<dim3(192, 64),  b256, 0, stream>>>(w_qkv,    wqkvT,   2048, 6144);
  transpose_cvt<<<dim3(64, 64),   b256, 0, stream>>>(w_ao,     waoT,    2048, 2048);
  transpose_cvt<<<dim3(256, 64),  b256, 0, stream>>>(w_ff_in,  wffinT,  2048, 8192);
  transpose_cvt<<<dim3(64, 256),  b256, 0, stream>>>(w_ff_out, wffoutT, 8192, 2048);
  ln_kernel<<<dim3(2048), b256, 0, stream>>>(x, ln_scale, ln_offset, h);
  gemm_bt<8><<<dim3(48, 16), b256, 0, stream>>>(h, wqkvT, nullptr, nullptr, nullptr, qkvb,
                                                2048, 6144, 2048);
  rope_kernel<<<dim3(2048, 16), dim3(128), 0, stream>>>(qkvb, qhb, khb, vTb);
  attn_kernel<<<dim3(32, 16), b256, 0, stream>>>(qhb, khb, vTb, avb);
  gemm_bt<0><<<dim3(16, 16), b256, 0, stream>>>(avb, waoT, nullptr, nullptr, out, nullptr,
                                                2048, 2048, 2048);
  gemm_bt<11><<<dim3(64, 16), b256, 0, stream>>>(h, wffinT, b_ff_in, nullptr, nullptr, ff1b,
                                                 2048, 8192, 2048);
  gemm_bt<5><<<dim3(16, 16), b256, 0, stream>>>(ff1b, wffoutT, b_ff_out, out, out, nullptr,
                                                2048, 2048, 8192);
}

// Round 2
// 512.905 us; speedup vs baseline: 1.2711x; 1.2711x over previous
//
#include <hip/hip_runtime.h>
#include <hip/hip_bf16.h>

using bf16_t = __hip_bfloat16;
typedef __attribute__((ext_vector_type(8))) __bf16 bfrag;   // 8 bf16 = 4 VGPR (MFMA A/B operand)
typedef __attribute__((ext_vector_type(4))) float f32x4;    // MFMA C/D operand

#define MFMA16(a, b, c) __builtin_amdgcn_mfma_f32_16x16x32_bf16((a), (b), (c), 0, 0, 0)

__device__ __forceinline__ void gload_lds16(const void* g, void* l) {
  // async global->LDS, 16B/lane; LDS dest = wave-uniform base + lane*16
  __builtin_amdgcn_global_load_lds((const __attribute__((address_space(1))) void*)g,
                                   (__attribute__((address_space(3))) void*)l, 16, 0, 0);
}

// ---------- weight transpose + f32->bf16 convert: in[K][N] f32 -> out[N][K] bf16 ----------
__global__ __launch_bounds__(256) void transpose_cvt(const float* __restrict__ in,
    bf16_t* __restrict__ out, int K, int N) {
  __shared__ float t[32][33];
  const int n0 = blockIdx.x * 32, k0 = blockIdx.y * 32;
  const int tx = threadIdx.x & 31, ty = threadIdx.x >> 5;   // 32 x 8
#pragma unroll
  for (int i = 0; i < 4; ++i)
    t[ty + i * 8][tx] = in[(size_t)(k0 + ty + i * 8) * N + n0 + tx];
  __syncthreads();
#pragma unroll
  for (int i = 0; i < 4; ++i)
    out[(size_t)(n0 + ty + i * 8) * K + k0 + tx] = bf16_t(t[tx][ty + i * 8]);
}

// ---------- LayerNorm: x f32 [2048][2048] -> h bf16 ----------
__global__ __launch_bounds__(256) void ln_kernel(const float* __restrict__ x,
    const float* __restrict__ sc, const float* __restrict__ of, bf16_t* __restrict__ h) {
  __shared__ float red[8];
  const int n = blockIdx.x, tid = threadIdx.x;
  const float* xr = x + (size_t)n * 2048;
  float4 a = ((const float4*)xr)[tid * 2];
  float4 b = ((const float4*)xr)[tid * 2 + 1];
  float s = a.x + a.y + a.z + a.w + b.x + b.y + b.z + b.w;
  float q = a.x * a.x + a.y * a.y + a.z * a.z + a.w * a.w +
            b.x * b.x + b.y * b.y + b.z * b.z + b.w * b.w;
#pragma unroll
  for (int m = 32; m; m >>= 1) { s += __shfl_xor(s, m); q += __shfl_xor(q, m); }
  if ((tid & 63) == 0) { red[(tid >> 6) * 2] = s; red[(tid >> 6) * 2 + 1] = q; }
  __syncthreads();
  s = red[0] + red[2] + red[4] + red[6];
  q = red[1] + red[3] + red[5] + red[7];
  const float mu = s * (1.f / 2048.f);
  const float inv = rsqrtf(q * (1.f / 2048.f) - mu * mu + 1e-5f);
  const int base = tid * 8;
  float v[8] = {a.x, a.y, a.z, a.w, b.x, b.y, b.z, b.w};
  bf16_t* hr = h + (size_t)n * 2048 + base;
#pragma unroll
  for (int j = 0; j < 8; ++j) hr[j] = bf16_t((v[j] - mu) * inv * sc[base + j] + of[base + j]);
}

// ---------- 8-phase 256x256 GEMM: C = A[M][lda](bf16, K cols used) * BT[N][ldb]^T ----------
// Per-split (blockIdx.z): A += z*K, BT += z*K, Cf += z*splitStride.
// EPI bits: 1=+bias[col], 2=gelu(tanh), 8=store bf16 to Cb (else f32 to Cf)
template <int EPI>
__global__ __launch_bounds__(512, 2) void gemm8p(
    const bf16_t* __restrict__ A, int lda, const bf16_t* __restrict__ BT, int ldb,
    const float* __restrict__ bias, float* __restrict__ Cf, bf16_t* __restrict__ Cb,
    int M, int N, int K, size_t splitStride) {
  extern __shared__ __align__(16) char lds[];   // 128 KiB: A slots [0,64K), B slots [64K,128K)
  const int tid = threadIdx.x, wid = tid >> 6, lane = tid & 63;
  const int lc = lane & 15, lg = lane >> 4;
  const int bm = blockIdx.y * 256, bn = blockIdx.x * 256;
  const int wr = wid >> 2, wc = wid & 3;              // 2 (M) x 4 (N) waves, each 128x64 out
  const int NT = K >> 6;                              // K-tiles of 64
  const bf16_t* Ab = A + (size_t)blockIdx.z * K;
  const bf16_t* Bb = BT + (size_t)blockIdx.z * K;
  // staging geometry: linear LDS o = j*8192 + wid*1024 + lane*16 -> row=o>>6, lgS=(o>>4)&3
  const int sr = wid * 16 + (lane >> 2);              // row (j=0); j=1 -> row = 128+sr
  const int lgp = (lane & 3) ^ ((sr >> 1) & 3);       // pre-swizzled global k-chunk

  // stage half-tile s: tile=s>>2, half s&3 (0:A-k0 1:B-k0 2:A-k1 3:B-k1); 2 gloads/thread
  auto stageS = [&](int s) {
    if (s >= 4 * NT) return;
    const int ts = s >> 2, hs = s & 3, dd = ts & 1, kk = hs >> 1;
    const int koff = ts * 64 + kk * 32;
    const int slotOff = ((hs & 1) ? 65536 : 0) + ((dd * 2 + kk) << 14);
    const bf16_t* X = (hs & 1) ? Bb : Ab;
    const int R0 = (hs & 1) ? bn : bm;
    const int ld = (hs & 1) ? ldb : lda;
    char* base = lds + slotOff + wid * 1024;
    gload_lds16(X + (size_t)(R0 + sr) * ld + koff + lgp * 8, base);
    gload_lds16(X + (size_t)(R0 + 128 + sr) * ld + koff + lgp * 8, base + 8192);
  };

#pragma unroll
  for (int s = 0; s < 7; ++s) stageS(s);              // tile0 full + tile1 {A-k0,B-k0,A-k1}
  asm volatile("s_waitcnt vmcnt(6)" ::: "memory");    // tile0's 4 halves landed
  __builtin_amdgcn_s_barrier();

  f32x4 acc[8][4] = {};
// swizzled fragment read: logical (row, lg) of a [256 rows][32 k] slot
#define FR(off, row) \
  (*(const bfrag*)(lds + (off) + (row) * 64 + ((lg ^ (((row) >> 1) & 3)) << 4)))

  for (int t = 0; t < NT; ++t) {
    const int d = t & 1;
    const int aoff0 = (d * 2 + 0) << 14, aoff1 = (d * 2 + 1) << 14;
    const int boff0 = 65536 + aoff0, boff1 = 65536 + aoff1;
    bfrag a[8];
    // ---- phase 0: kk=0, ch=0 (reads A-k0 frags + B-k0 n=0,1; stages (t+1).B-k1)
    {
#pragma unroll
      for (int m = 0; m < 8; ++m) a[m] = FR(aoff0, wr * 128 + m * 16 + lc);
      bfrag b0 = FR(boff0, wc * 64 + lc);
      bfrag b1 = FR(boff0, wc * 64 + 16 + lc);
      stageS(4 * t + 7);
      __builtin_amdgcn_s_barrier();
      asm volatile("s_waitcnt lgkmcnt(0)" ::: "memory");
      __builtin_amdgcn_sched_barrier(0);
      __builtin_amdgcn_s_setprio(1);
#pragma unroll
      for (int m = 0; m < 8; ++m) {
        acc[m][0] = MFMA16(a[m], b0, acc[m][0]);
        acc[m][1] = MFMA16(a[m], b1, acc[m][1]);
      }
      __builtin_amdgcn_s_setprio(0);
      __builtin_amdgcn_s_barrier();
    }
    // ---- phase 1: kk=0, ch=1 (reuses a[]; B-k0 n=2,3; stages (t+2).A-k0)
    {
      bfrag b2 = FR(boff0, wc * 64 + 32 + lc);
      bfrag b3 = FR(boff0, wc * 64 + 48 + lc);
      stageS(4 * t + 8);
      __builtin_amdgcn_s_barrier();
      asm volatile("s_waitcnt lgkmcnt(0)" ::: "memory");
      __builtin_amdgcn_sched_barrier(0);
      __builtin_amdgcn_s_setprio(1);
#pragma unroll
      for (int m = 0; m < 8; ++m) {
        acc[m][2] = MFMA16(a[m], b2, acc[m][2]);
        acc[m][3] = MFMA16(a[m], b3, acc[m][3]);
      }
      __builtin_amdgcn_s_setprio(0);
      __builtin_amdgcn_s_barrier();
    }
    // ---- phase 2: kk=1, ch=0 (reloads a[] from A-k1; B-k1 n=0,1; stages (t+2).B-k0)
    {
#pragma unroll
      for (int m = 0; m < 8; ++m) a[m] = FR(aoff1, wr * 128 + m * 16 + lc);
      bfrag b0 = FR(boff1, wc * 64 + lc);
      bfrag b1 = FR(boff1, wc * 64 + 16 + lc);
      stageS(4 * t + 9);
      __builtin_amdgcn_s_barrier();
      asm volatile("s_waitcnt lgkmcnt(0)" ::: "memory");
      __builtin_amdgcn_sched_barrier(0);
      __builtin_amdgcn_s_setprio(1);
#pragma unroll
      for (int m = 0; m < 8; ++m) {
        acc[m][0] = MFMA16(a[m], b0, acc[m][0]);
        acc[m][1] = MFMA16(a[m], b1, acc[m][1]);
      }
      __builtin_amdgcn_s_setprio(0);
      __builtin_amdgcn_s_barrier();
    }
    // ---- phase 3: kk=1, ch=1 (+ end-of-tile counted vmcnt; stages (t+2).A-k1)
    {
      bfrag b2 = FR(boff1, wc * 64 + 32 + lc);
      bfrag b3 = FR(boff1, wc * 64 + 48 + lc);
      stageS(4 * t + 10);
      __builtin_amdgcn_s_barrier();
      asm volatile("s_waitcnt lgkmcnt(0)" ::: "memory");
      __builtin_amdgcn_sched_barrier(0);
      __builtin_amdgcn_s_setprio(1);
#pragma unroll
      for (int m = 0; m < 8; ++m) {
        acc[m][2] = MFMA16(a[m], b2, acc[m][2]);
        acc[m][3] = MFMA16(a[m], b3, acc[m][3]);
      }
      __builtin_amdgcn_s_setprio(0);
      if (t < NT - 2) asm volatile("s_waitcnt vmcnt(6)" ::: "memory");  // 3 halves in flight
      else            asm volatile("s_waitcnt vmcnt(0)" ::: "memory");  // epilogue drain
      __builtin_amdgcn_s_barrier();
    }
  }
#undef FR
  // ---- epilogue
  float* Cfz = Cf + (size_t)blockIdx.z * splitStride;
  const int row0 = bm + wr * 128 + lg * 4;
  const int col0 = bn + wc * 64 + lc;
#pragma unroll
  for (int m = 0; m < 8; ++m) {
#pragma unroll
    for (int n = 0; n < 4; ++n) {
      const int col = col0 + n * 16;
      float bv = (EPI & 1) ? bias[col] : 0.f;
#pragma unroll
      for (int i = 0; i < 4; ++i) {
        const int row = row0 + m * 16 + i;
        float v = acc[m][n][i];
        if (EPI & 1) v += bv;
        if (EPI & 2) v = 0.5f * v * (1.f + tanhf(0.7978845608028654f * (v + 0.044715f * v * v * v)));
        if (EPI & 8) Cb[(size_t)row * N + col] = bf16_t(v);
        else         Cfz[(size_t)row * N + col] = v;
      }
    }
  }
}

// ---------- split-K partial reduction (+optional bias, +optional accumulate into out) ----------
template <int NP, bool ADDIN, bool BIAS>
__global__ __launch_bounds__(256) void reduceP(const float* __restrict__ p0,
    const float* __restrict__ p1, const float* __restrict__ p2,
    const float* __restrict__ p3, const float* __restrict__ bias,
    float* __restrict__ out, int total, int colmask) {
  const int i = (blockIdx.x * 256 + threadIdx.x) * 4;
  if (i >= total) return;
  float4 v = *(const float4*)(p0 + i);
  float4 w = *(const float4*)(p1 + i);
  v.x += w.x; v.y += w.y; v.z += w.z; v.w += w.w;
  if (NP == 4) {
    float4 u = *(const float4*)(p2 + i);
    float4 z = *(const float4*)(p3 + i);
    v.x += u.x + z.x; v.y += u.y + z.y; v.z += u.z + z.z; v.w += u.w + z.w;
  }
  if (BIAS) {
    float4 b = *(const float4*)(bias + (i & colmask));
    v.x += b.x; v.y += b.y; v.z += b.z; v.w += b.w;
  }
  if (ADDIN) {
    float4 o = *(const float4*)(out + i);
    v.x += o.x; v.y += o.y; v.z += o.z; v.w += o.w;
  }
  *(float4*)(out + i) = v;
}

// ---------- RoPE + head split: qkv bf16 [2048][6144] -> qh/kh [16][2048][128], vT [16][128][2048] ----------
__global__ __launch_bounds__(128) void rope_kernel(const bf16_t* __restrict__ qkv,
    bf16_t* __restrict__ qh, bf16_t* __restrict__ kh, bf16_t* __restrict__ vT) {
  const int n = blockIdx.x, hh = blockIdx.y;
  const int d = threadIdx.x;
  const int mp = hh >> 2, hi = hh & 3;
  const bf16_t* row = qkv + (size_t)n * 6144 + mp * 1536 + hi * 128;  // [q|v|k] each 512 per mp
  float q = __bfloat162float(row[d]);
  float k = __bfloat162float(row[1024 + d]);
  if (d < 64) {  // wave-uniform branch (wave 0 = lanes 0..63)
    const float ang = (float)n * powf(10000.f, -(float)(d & ~1) / 64.f);
    const float sn = sinf(ang), cs = cosf(ang);
    const float qp = __shfl_xor(q, 1), kp = __shfl_xor(k, 1);
    if (d & 1) { q = q * cs + qp * sn; k = k * cs + kp * sn; }
    else       { q = q * cs - qp * sn; k = k * cs - kp * sn; }
  }
  qh[((size_t)hh * 2048 + n) * 128 + d] = bf16_t(q * 0.08838834764831845f); // 1/sqrt(128)
  kh[((size_t)hh * 2048 + n) * 128 + d] = bf16_t(k);
  vT[((size_t)hh * 128 + d) * 2048 + n] = row[512 + d];
}

// ---------- causal flash attention: 1 block = (head, 64 q-rows), 4 waves x 16 rows ----------
__global__ __launch_bounds__(256) void attn_kernel(const bf16_t* __restrict__ qh,
    const bf16_t* __restrict__ kh, const bf16_t* __restrict__ vT, bf16_t* __restrict__ av) {
  __shared__ alignas(16) bf16_t Ks[64 * 128];   // [kv][d] 16KB
  __shared__ alignas(16) bf16_t Vs[128 * 64];   // [d][kv] 16KB
  __shared__ alignas(16) bf16_t Ps[4][16 * 64]; // per-wave P 8KB
  const int qt = blockIdx.x, h = blockIdx.y;
  const int tid = threadIdx.x, wid = tid >> 6, lane = tid & 63;
  const int lc = lane & 15, lg = lane >> 4;
  const int qr = qt * 64 + wid * 16;
  const bf16_t* Qb = qh + ((size_t)h * 2048 + qr) * 128;
  bfrag qf[4];
#pragma unroll
  for (int ks = 0; ks < 4; ++ks)
    qf[ks] = *(const bfrag*)&Qb[lc * 128 + ks * 32 + lg * 8];
  f32x4 O[8] = {};
  float mr[4] = {-1e30f, -1e30f, -1e30f, -1e30f};
  float lsum[4] = {0.f, 0.f, 0.f, 0.f};
  for (int kt = 0; kt <= qt; ++kt) {
    const int kv0 = kt * 64;
    __syncthreads();
#pragma unroll
    for (int i = 0; i < 4; ++i) {
      const int e = i * 2048 + tid * 8;
      gload_lds16(kh + ((size_t)h * 2048 + kv0 + (e >> 7)) * 128 + (e & 127),
                  (char*)Ks + i * 4096 + wid * 1024);
      gload_lds16(vT + ((size_t)h * 128 + (e >> 6)) * 2048 + kv0 + (e & 63),
                  (char*)Vs + i * 4096 + wid * 1024);
    }
    __syncthreads();
    f32x4 s[4];
#pragma unroll
    for (int c = 0; c < 4; ++c) {
      f32x4 a = {};
#pragma unroll
      for (int ks = 0; ks < 4; ++ks) {
        bfrag kf = *(const bfrag*)&Ks[(c * 16 + lc) * 128 + ks * 32 + lg * 8];
        a = __builtin_amdgcn_mfma_f32_16x16x32_bf16(qf[ks], kf, a, 0, 0, 0);
      }
      s[c] = a;
    }
    if (kv0 + 63 > qr) {  // diagonal tile: causal mask
#pragma unroll
      for (int c = 0; c < 4; ++c)
#pragma unroll
        for (int i = 0; i < 4; ++i)
          if (kv0 + c * 16 + lc > qr + lg * 4 + i) s[c][i] = -1e10f;
    }
    float pm[4];
#pragma unroll
    for (int i = 0; i < 4; ++i)
      pm[i] = fmaxf(fmaxf(s[0][i], s[1][i]), fmaxf(s[2][i], s[3][i]));
#pragma unroll
    for (int m = 1; m < 16; m <<= 1)
#pragma unroll
      for (int i = 0; i < 4; ++i) pm[i] = fmaxf(pm[i], __shfl_xor(pm[i], m));
    float al[4], rs[4];
#pragma unroll
    for (int i = 0; i < 4; ++i) {
      const float mn = fmaxf(mr[i], pm[i]);
      al[i] = __expf(mr[i] - mn);
      mr[i] = mn;
      rs[i] = 0.f;
    }
#pragma unroll
    for (int c = 0; c < 4; ++c)
#pragma unroll
      for (int i = 0; i < 4; ++i) {
        const float p = __expf(s[c][i] - mr[i]);
        s[c][i] = p; rs[i] += p;
      }
#pragma unroll
    for (int m = 1; m < 16; m <<= 1)
#pragma unroll
      for (int i = 0; i < 4; ++i) rs[i] += __shfl_xor(rs[i], m);
#pragma unroll
    for (int i = 0; i < 4; ++i) lsum[i] = lsum[i] * al[i] + rs[i];
#pragma unroll
    for (int n = 0; n < 8; ++n)
#pragma unroll
      for (int i = 0; i < 4; ++i) O[n][i] *= al[i];
#pragma unroll
    for (int c = 0; c < 4; ++c)
#pragma unroll
      for (int i = 0; i < 4; ++i)
        Ps[wid][(lg * 4 + i) * 64 + c * 16 + lc] = bf16_t(s[c][i]);
#pragma unroll
    for (int k2 = 0; k2 < 2; ++k2) {
      bfrag pf = *(const bfrag*)&Ps[wid][lc * 64 + k2 * 32 + lg * 8];
#pragma unroll
      for (int n = 0; n < 8; ++n) {
        bfrag vf = *(const bfrag*)&Vs[(n * 16 + lc) * 64 + k2 * 32 + lg * 8];
        O[n] = __builtin_amdgcn_mfma_f32_16x16x32_bf16(pf, vf, O[n], 0, 0, 0);
      }
    }
  }
#pragma unroll
  for (int n = 0; n < 8; ++n)
#pragma unroll
    for (int i = 0; i < 4; ++i)
      av[(size_t)(qr + lg * 4 + i) * 2048 + h * 128 + n * 16 + lc] = bf16_t(O[n][i] / lsum[i]);
}

extern "C" void kernel_launch(void* const* d_in, const int* in_sizes, int n_in,
                              void* d_out, int out_size, void* d_ws, size_t ws_size,
                              hipStream_t stream) {
  const float* x        = (const float*)d_in[0];
  const float* ln_scale = (const float*)d_in[1];
  const float* ln_offset= (const float*)d_in[2];
  const float* w_qkv    = (const float*)d_in[3];   // [2048][6144]
  const float* w_ao     = (const float*)d_in[4];   // [2048][2048]
  const float* w_ff_in  = (const float*)d_in[5];   // [2048][8192]
  const float* b_ff_in  = (const float*)d_in[6];   // [8192]
  const float* w_ff_out = (const float*)d_in[7];   // [8192][2048]
  const float* b_ff_out = (const float*)d_in[8];   // [2048]
  float* out = (float*)d_out;

  char* ws = (char*)d_ws;
  bf16_t* wqkvT   = (bf16_t*)(ws);                  // [6144][2048]  (dead after qkv GEMM)
  bf16_t* waoT    = (bf16_t*)(ws + 25165824);       // [2048][2048]  (dead after attn_out)
  bf16_t* wffinT  = (bf16_t*)(ws + 33554432);       // [8192][2048]  (dead after ff_in)
  bf16_t* wffoutT = (bf16_t*)(ws + 67108864);       // [2048][8192]
  bf16_t* h       = (bf16_t*)(ws + 100663296);      // [2048][2048]
  bf16_t* qhb     = (bf16_t*)(ws + 109051904);      // [16][2048][128]
  bf16_t* khb     = (bf16_t*)(ws + 117440512);
  bf16_t* vTb     = (bf16_t*)(ws + 125829120);      // [16][128][2048]
  bf16_t* avb     = (bf16_t*)(ws + 134217728);      // [2048][2048]
  bf16_t* qkvb    = (bf16_t*)(ws + 142606336);      // [2048][6144]; later ff1 [2048][8192]
  bf16_t* ff1b    = qkvb;
  float*  pa      = (float*)(ws + 142606336);       // attn_out partials 2x[2048][2048] f32 (over dead qkvb)
  float*  pf      = (float*)(ws);                   // ff_out partials 4x[2048][2048] f32 (over dead weights)

  hipFuncSetAttribute((const void*)gemm8p<0>,  hipFuncAttributeMaxDynamicSharedMemorySize, 131072);
  hipFuncSetAttribute((const void*)gemm8p<8>,  hipFuncAttributeMaxDynamicSharedMemorySize, 131072);
  hipFuncSetAttribute((const void*)gemm8p<11>, hipFuncAttributeMaxDynamicSharedMemorySize, 131072);

  dim3 b256(256), b512(512);
  transpose_cvt<<<dim3(192, 64),  b256, 0, stream>>>(w_qkv,    wqkvT,   2048, 6144);
  transpose_cvt<<<dim3(64, 64),   b256, 0, stream>>>(w_ao,     waoT,    2048, 2048);
  transpose_cvt<<<dim3(256, 64),  b256, 0, stream>>>(w_ff_in,  wffinT,  2048, 8192);
  transpose_cvt<<<dim3(64, 256),  b256, 0, stream>>>(w_ff_out, wffoutT, 8192, 2048);
  ln_kernel<<<dim3(2048), b256, 0, stream>>>(x, ln_scale, ln_offset, h);

  gemm8p<8><<<dim3(24, 8, 1), b512, 131072, stream>>>(h, 2048, wqkvT, 2048,
      nullptr, nullptr, qkvb, 2048, 6144, 2048, 0);
  rope_kernel<<<dim3(2048, 16), dim3(128), 0, stream>>>(qkvb, qhb, khb, vTb);
  attn_kernel<<<dim3(32, 16), b256, 0, stream>>>(qhb, khb, vTb, avb);

  // attn_out: split-K=2 (K=1024 each), partials in dead qkvb region (contiguous)
  gemm8p<0><<<dim3(8, 8, 2), b512, 131072, stream>>>(avb, 2048, waoT, 2048,
      nullptr, pa, nullptr, 2048, 2048, 1024, (size_t)2048 * 2048);
  reduceP<2, false, false><<<dim3(4096), b256, 0, stream>>>(pa, pa + 4194304,
      nullptr, nullptr, nullptr, out, 4194304, 2047);

  gemm8p<11><<<dim3(32, 8, 1), b512, 131072, stream>>>(h, 2048, wffinT, 2048,
      b_ff_in, nullptr, ff1b, 2048, 8192, 2048, 0);

  // ff_out: split-K=4 (K=2048 each), partials over dead wqkvT/waoT/wffinT region
  gemm8p<0><<<dim3(8, 8, 4), b512, 131072, stream>>>(ff1b, 8192, wffoutT, 8192,
      nullptr, pf, nullptr, 2048, 2048, 2048, (size_t)2048 * 2048);
  reduceP<4, true, true><<<dim3(4096), b256, 0, stream>>>(pf, pf + 4194304,
      pf + 2 * 4194304, pf + 3 * 4194304, b_ff_out, out, 4194304, 2047);
}

// Round 3
// 446.838 us; speedup vs baseline: 1.4590x; 1.1479x over previous
//
#include <hip/hip_runtime.h>
#include <hip/hip_bf16.h>

using bf16_t = __hip_bfloat16;
typedef __attribute__((ext_vector_type(8))) __bf16 bfrag;   // 8 bf16 = 4 VGPR (MFMA A/B operand)
typedef __attribute__((ext_vector_type(4))) float f32x4;    // MFMA C/D operand

#define MFMA16(a, b, c) __builtin_amdgcn_mfma_f32_16x16x32_bf16((a), (b), (c), 0, 0, 0)

__device__ __forceinline__ void gload_lds16(const void* g, void* l) {
  // async global->LDS, 16B/lane; LDS dest = wave-uniform base + lane*16
  __builtin_amdgcn_global_load_lds((const __attribute__((address_space(1))) void*)g,
                                   (__attribute__((address_space(3))) void*)l, 16, 0, 0);
}

// ---------- weight transpose + f32->bf16 convert: in[K][N] f32 -> out[N][K] bf16 ----------
__global__ __launch_bounds__(256) void transpose_cvt(const float* __restrict__ in,
    bf16_t* __restrict__ out, int K, int N) {
  __shared__ float t[32][33];
  const int n0 = blockIdx.x * 32, k0 = blockIdx.y * 32;
  const int tx = threadIdx.x & 31, ty = threadIdx.x >> 5;   // 32 x 8
#pragma unroll
  for (int i = 0; i < 4; ++i)
    t[ty + i * 8][tx] = in[(size_t)(k0 + ty + i * 8) * N + n0 + tx];
  __syncthreads();
#pragma unroll
  for (int i = 0; i < 4; ++i)
    out[(size_t)(n0 + ty + i * 8) * K + k0 + tx] = bf16_t(t[tx][ty + i * 8]);
}

// ---------- LayerNorm: x f32 [2048][2048] -> h bf16 ----------
__global__ __launch_bounds__(256) void ln_kernel(const float* __restrict__ x,
    const float* __restrict__ sc, const float* __restrict__ of, bf16_t* __restrict__ h) {
  __shared__ float red[8];
  const int n = blockIdx.x, tid = threadIdx.x;
  const float* xr = x + (size_t)n * 2048;
  float4 a = ((const float4*)xr)[tid * 2];
  float4 b = ((const float4*)xr)[tid * 2 + 1];
  float s = a.x + a.y + a.z + a.w + b.x + b.y + b.z + b.w;
  float q = a.x * a.x + a.y * a.y + a.z * a.z + a.w * a.w +
            b.x * b.x + b.y * b.y + b.z * b.z + b.w * b.w;
#pragma unroll
  for (int m = 32; m; m >>= 1) { s += __shfl_xor(s, m); q += __shfl_xor(q, m); }
  if ((tid & 63) == 0) { red[(tid >> 6) * 2] = s; red[(tid >> 6) * 2 + 1] = q; }
  __syncthreads();
  s = red[0] + red[2] + red[4] + red[6];
  q = red[1] + red[3] + red[5] + red[7];
  const float mu = s * (1.f / 2048.f);
  const float inv = rsqrtf(q * (1.f / 2048.f) - mu * mu + 1e-5f);
  const int base = tid * 8;
  float v[8] = {a.x, a.y, a.z, a.w, b.x, b.y, b.z, b.w};
  bf16_t* hr = h + (size_t)n * 2048 + base;
#pragma unroll
  for (int j = 0; j < 8; ++j) hr[j] = bf16_t((v[j] - mu) * inv * sc[base + j] + of[base + j]);
}

// ---------- 8-phase 256x256 GEMM: C = A[M][lda](bf16, K cols used) * BT[N][ldb]^T ----------
// EPI bits: 1=+bias[col], 2=gelu(tanh), 8=store bf16 to Cb (else f32 to Cf)
template <int EPI>
__global__ __launch_bounds__(512, 2) void gemm8p(
    const bf16_t* __restrict__ A, int lda, const bf16_t* __restrict__ BT, int ldb,
    const float* __restrict__ bias, float* __restrict__ Cf, bf16_t* __restrict__ Cb,
    int M, int N, int K, size_t splitStride) {
  extern __shared__ __align__(16) char lds[];   // 128 KiB: A slots [0,64K), B slots [64K,128K)
  const int tid = threadIdx.x, wid = tid >> 6, lane = tid & 63;
  const int lc = lane & 15, lg = lane >> 4;
  const int bm = blockIdx.y * 256, bn = blockIdx.x * 256;
  const int wr = wid >> 2, wc = wid & 3;              // 2 (M) x 4 (N) waves, each 128x64 out
  const int NT = K >> 6;                              // K-tiles of 64
  const bf16_t* Ab = A + (size_t)blockIdx.z * K;
  const bf16_t* Bb = BT + (size_t)blockIdx.z * K;
  const int sr = wid * 16 + (lane >> 2);              // staging row (j=0); j=1 -> +128
  const int lgp = (lane & 3) ^ ((sr >> 1) & 3);       // pre-swizzled global k-chunk

  auto stageS = [&](int s) {
    if (s >= 4 * NT) return;
    const int ts = s >> 2, hs = s & 3, dd = ts & 1, kk = hs >> 1;
    const int koff = ts * 64 + kk * 32;
    const int slotOff = ((hs & 1) ? 65536 : 0) + ((dd * 2 + kk) << 14);
    const bf16_t* X = (hs & 1) ? Bb : Ab;
    const int R0 = (hs & 1) ? bn : bm;
    const int ld = (hs & 1) ? ldb : lda;
    char* base = lds + slotOff + wid * 1024;
    gload_lds16(X + (size_t)(R0 + sr) * ld + koff + lgp * 8, base);
    gload_lds16(X + (size_t)(R0 + 128 + sr) * ld + koff + lgp * 8, base + 8192);
  };

#pragma unroll
  for (int s = 0; s < 7; ++s) stageS(s);              // tile0 full + tile1 {A-k0,B-k0,A-k1}
  asm volatile("s_waitcnt vmcnt(6)" ::: "memory");    // tile0's 4 halves landed
  __builtin_amdgcn_s_barrier();

  f32x4 acc[8][4] = {};
#define FR(off, row) \
  (*(const bfrag*)(lds + (off) + (row) * 64 + ((lg ^ (((row) >> 1) & 3)) << 4)))

  for (int t = 0; t < NT; ++t) {
    const int d = t & 1;
    const int aoff0 = (d * 2 + 0) << 14, aoff1 = (d * 2 + 1) << 14;
    const int boff0 = 65536 + aoff0, boff1 = 65536 + aoff1;
    bfrag a[8];
    {
#pragma unroll
      for (int m = 0; m < 8; ++m) a[m] = FR(aoff0, wr * 128 + m * 16 + lc);
      bfrag b0 = FR(boff0, wc * 64 + lc);
      bfrag b1 = FR(boff0, wc * 64 + 16 + lc);
      stageS(4 * t + 7);
      __builtin_amdgcn_s_barrier();
      asm volatile("s_waitcnt lgkmcnt(0)" ::: "memory");
      __builtin_amdgcn_sched_barrier(0);
      __builtin_amdgcn_s_setprio(1);
#pragma unroll
      for (int m = 0; m < 8; ++m) {
        acc[m][0] = MFMA16(a[m], b0, acc[m][0]);
        acc[m][1] = MFMA16(a[m], b1, acc[m][1]);
      }
      __builtin_amdgcn_s_setprio(0);
      __builtin_amdgcn_s_barrier();
    }
    {
      bfrag b2 = FR(boff0, wc * 64 + 32 + lc);
      bfrag b3 = FR(boff0, wc * 64 + 48 + lc);
      stageS(4 * t + 8);
      __builtin_amdgcn_s_barrier();
      asm volatile("s_waitcnt lgkmcnt(0)" ::: "memory");
      __builtin_amdgcn_sched_barrier(0);
      __builtin_amdgcn_s_setprio(1);
#pragma unroll
      for (int m = 0; m < 8; ++m) {
        acc[m][2] = MFMA16(a[m], b2, acc[m][2]);
        acc[m][3] = MFMA16(a[m], b3, acc[m][3]);
      }
      __builtin_amdgcn_s_setprio(0);
      __builtin_amdgcn_s_barrier();
    }
    {
#pragma unroll
      for (int m = 0; m < 8; ++m) a[m] = FR(aoff1, wr * 128 + m * 16 + lc);
      bfrag b0 = FR(boff1, wc * 64 + lc);
      bfrag b1 = FR(boff1, wc * 64 + 16 + lc);
      stageS(4 * t + 9);
      __builtin_amdgcn_s_barrier();
      asm volatile("s_waitcnt lgkmcnt(0)" ::: "memory");
      __builtin_amdgcn_sched_barrier(0);
      __builtin_amdgcn_s_setprio(1);
#pragma unroll
      for (int m = 0; m < 8; ++m) {
        acc[m][0] = MFMA16(a[m], b0, acc[m][0]);
        acc[m][1] = MFMA16(a[m], b1, acc[m][1]);
      }
      __builtin_amdgcn_s_setprio(0);
      __builtin_amdgcn_s_barrier();
    }
    {
      bfrag b2 = FR(boff1, wc * 64 + 32 + lc);
      bfrag b3 = FR(boff1, wc * 64 + 48 + lc);
      stageS(4 * t + 10);
      __builtin_amdgcn_s_barrier();
      asm volatile("s_waitcnt lgkmcnt(0)" ::: "memory");
      __builtin_amdgcn_sched_barrier(0);
      __builtin_amdgcn_s_setprio(1);
#pragma unroll
      for (int m = 0; m < 8; ++m) {
        acc[m][2] = MFMA16(a[m], b2, acc[m][2]);
        acc[m][3] = MFMA16(a[m], b3, acc[m][3]);
      }
      __builtin_amdgcn_s_setprio(0);
      if (t < NT - 2) asm volatile("s_waitcnt vmcnt(6)" ::: "memory");
      else            asm volatile("s_waitcnt vmcnt(0)" ::: "memory");
      __builtin_amdgcn_s_barrier();
    }
  }
#undef FR
  float* Cfz = Cf + (size_t)blockIdx.z * splitStride;
  const int row0 = bm + wr * 128 + lg * 4;
  const int col0 = bn + wc * 64 + lc;
#pragma unroll
  for (int m = 0; m < 8; ++m) {
#pragma unroll
    for (int n = 0; n < 4; ++n) {
      const int col = col0 + n * 16;
      float bv = (EPI & 1) ? bias[col] : 0.f;
#pragma unroll
      for (int i = 0; i < 4; ++i) {
        const int row = row0 + m * 16 + i;
        float v = acc[m][n][i];
        if (EPI & 1) v += bv;
        if (EPI & 2) v = 0.5f * v * (1.f + tanhf(0.7978845608028654f * (v + 0.044715f * v * v * v)));
        if (EPI & 8) Cb[(size_t)row * N + col] = bf16_t(v);
        else         Cfz[(size_t)row * N + col] = v;
      }
    }
  }
}

// ---------- split-K partial reduction ----------
template <int NP, bool ADDIN, bool BIAS>
__global__ __launch_bounds__(256) void reduceP(const float* __restrict__ p0,
    const float* __restrict__ p1, const float* __restrict__ p2,
    const float* __restrict__ p3, const float* __restrict__ bias,
    float* __restrict__ out, int total, int colmask) {
  const int i = (blockIdx.x * 256 + threadIdx.x) * 4;
  if (i >= total) return;
  float4 v = *(const float4*)(p0 + i);
  float4 w = *(const float4*)(p1 + i);
  v.x += w.x; v.y += w.y; v.z += w.z; v.w += w.w;
  if (NP == 4) {
    float4 u = *(const float4*)(p2 + i);
    float4 z = *(const float4*)(p3 + i);
    v.x += u.x + z.x; v.y += u.y + z.y; v.z += u.z + z.z; v.w += u.w + z.w;
  }
  if (BIAS) {
    float4 b = *(const float4*)(bias + (i & colmask));
    v.x += b.x; v.y += b.y; v.z += b.z; v.w += b.w;
  }
  if (ADDIN) {
    float4 o = *(const float4*)(out + i);
    v.x += o.x; v.y += o.y; v.z += o.z; v.w += o.w;
  }
  *(float4*)(out + i) = v;
}

// ---------- RoPE + head split ----------
__global__ __launch_bounds__(128) void rope_kernel(const bf16_t* __restrict__ qkv,
    bf16_t* __restrict__ qh, bf16_t* __restrict__ kh, bf16_t* __restrict__ vT) {
  const int n = blockIdx.x, hh = blockIdx.y;
  const int d = threadIdx.x;
  const int mp = hh >> 2, hi = hh & 3;
  const bf16_t* row = qkv + (size_t)n * 6144 + mp * 1536 + hi * 128;  // [q|v|k] each 512 per mp
  float q = __bfloat162float(row[d]);
  float k = __bfloat162float(row[1024 + d]);
  if (d < 64) {  // wave-uniform branch
    const float ang = (float)n * powf(10000.f, -(float)(d & ~1) / 64.f);
    const float sn = sinf(ang), cs = cosf(ang);
    const float qp = __shfl_xor(q, 1), kp = __shfl_xor(k, 1);
    if (d & 1) { q = q * cs + qp * sn; k = k * cs + kp * sn; }
    else       { q = q * cs - qp * sn; k = k * cs - kp * sn; }
  }
  qh[((size_t)hh * 2048 + n) * 128 + d] = bf16_t(q * 0.08838834764831845f); // 1/sqrt(128)
  kh[((size_t)hh * 2048 + n) * 128 + d] = bf16_t(k);
  vT[((size_t)hh * 128 + d) * 2048 + n] = row[512 + d];
}

// ---------- causal flash attention, load-balanced pairs + swizzled dbuf LDS ----------
// block = (pair p, head h); processes q-tiles {p, 31-p}: exactly 33 kv-iters each.
// 4 waves x 16 q-rows. K/V double-buffered, chunk-XOR swizzled; counted staging.
__global__ __launch_bounds__(256) void attn_kernel(const bf16_t* __restrict__ qh,
    const bf16_t* __restrict__ kh, const bf16_t* __restrict__ vT, bf16_t* __restrict__ av) {
  __shared__ alignas(16) char Kbuf[2][16384];    // [kv 64][d 128] bf16, chunk ^= row&15
  __shared__ alignas(16) char Vbuf[2][16384];    // [d 128][kv 64] bf16, chunk ^= row&7
  __shared__ alignas(16) bf16_t Ps[4][16 * 72];  // per-wave P, stride 72 (144B rows)
  const int p = blockIdx.x, h = blockIdx.y;
  const int tid = threadIdx.x, wid = tid >> 6, lane = tid & 63;
  const int lc = lane & 15, lg = lane >> 4;
  // staging geometry (per i-chunk): lds byte o = i*4096 + wid*1024 + lane*16
  const int krow = wid * 4 + (lane >> 4);        // + i*16 ; stored chunk = lane&15
  const int vrow = wid * 8 + (lane >> 3);        // + i*32 ; stored chunk = lane&7

  auto stage = [&](int kv0, int d) {
#pragma unroll
    for (int i = 0; i < 4; ++i) {
      const int kr = i * 16 + krow;
      const int kch = (lane & 15) ^ (kr & 15);   // pre-swizzled global chunk
      gload_lds16(kh + ((size_t)h * 2048 + kv0 + kr) * 128 + kch * 8,
                  Kbuf[d] + i * 4096 + wid * 1024);
      const int vr = i * 32 + vrow;
      const int vch = (lane & 7) ^ (vr & 7);
      gload_lds16(vT + ((size_t)h * 128 + vr) * 2048 + kv0 + vch * 8,
                  Vbuf[d] + i * 4096 + wid * 1024);
    }
  };
#define FRK(d, row, ch) (*(const bfrag*)(Kbuf[d] + (row) * 256 + (((ch) ^ ((row) & 15)) << 4)))
#define FRV(d, row, ch) (*(const bfrag*)(Vbuf[d] + (row) * 128 + (((ch) ^ ((row) & 7)) << 4)))

#pragma unroll 1
  for (int half = 0; half < 2; ++half) {
    const int qt = half ? (31 - p) : p;
    const int nkv = qt + 1;
    const int qr = qt * 64 + wid * 16;
    const bf16_t* Qb = qh + ((size_t)h * 2048 + qr) * 128;
    bfrag qf[4];
#pragma unroll
    for (int ks = 0; ks < 4; ++ks)
      qf[ks] = *(const bfrag*)&Qb[lc * 128 + ks * 32 + lg * 8];
    f32x4 O[8] = {};
    float mr[4] = {-1e30f, -1e30f, -1e30f, -1e30f};
    float lsum[4] = {0.f, 0.f, 0.f, 0.f};

    stage(0, 0);
    asm volatile("s_waitcnt vmcnt(0)" ::: "memory");
    __builtin_amdgcn_s_barrier();

#pragma unroll 1
    for (int kt = 0; kt < nkv; ++kt) {
      const int d = kt & 1;
      const int kv0 = kt * 64;
      if (kt + 1 < nkv) stage(kv0 + 64, d ^ 1);  // overlap with compute
      f32x4 s[4];
#pragma unroll
      for (int c = 0; c < 4; ++c) {
        f32x4 a = {};
#pragma unroll
        for (int ks = 0; ks < 4; ++ks) {
          bfrag kf = FRK(d, c * 16 + lc, ks * 4 + lg);
          a = MFMA16(qf[ks], kf, a);
        }
        s[c] = a;
      }
      if (kt == qt) {  // diagonal tile: causal mask
#pragma unroll
        for (int c = 0; c < 4; ++c)
#pragma unroll
          for (int i = 0; i < 4; ++i)
            if (kv0 + c * 16 + lc > qr + lg * 4 + i) s[c][i] = -1e10f;
      }
      float pm[4];
#pragma unroll
      for (int i = 0; i < 4; ++i)
        pm[i] = fmaxf(fmaxf(s[0][i], s[1][i]), fmaxf(s[2][i], s[3][i]));
#pragma unroll
      for (int m = 1; m < 16; m <<= 1)
#pragma unroll
        for (int i = 0; i < 4; ++i) pm[i] = fmaxf(pm[i], __shfl_xor(pm[i], m));
      float al[4], rs[4];
#pragma unroll
      for (int i = 0; i < 4; ++i) {
        const float mn = fmaxf(mr[i], pm[i]);
        al[i] = __expf(mr[i] - mn);
        mr[i] = mn;
        rs[i] = 0.f;
      }
#pragma unroll
      for (int c = 0; c < 4; ++c)
#pragma unroll
        for (int i = 0; i < 4; ++i) {
          const float pv = __expf(s[c][i] - mr[i]);
          s[c][i] = pv; rs[i] += pv;
        }
#pragma unroll
      for (int m = 1; m < 16; m <<= 1)
#pragma unroll
        for (int i = 0; i < 4; ++i) rs[i] += __shfl_xor(rs[i], m);
#pragma unroll
      for (int i = 0; i < 4; ++i) lsum[i] = lsum[i] * al[i] + rs[i];
#pragma unroll
      for (int n = 0; n < 8; ++n)
#pragma unroll
        for (int i = 0; i < 4; ++i) O[n][i] *= al[i];
#pragma unroll
      for (int c = 0; c < 4; ++c)
#pragma unroll
        for (int i = 0; i < 4; ++i)
          Ps[wid][(lg * 4 + i) * 72 + c * 16 + lc] = bf16_t(s[c][i]);
#pragma unroll
      for (int k2 = 0; k2 < 2; ++k2) {
        bfrag pf = *(const bfrag*)((const char*)&Ps[wid][0] + lc * 144 + k2 * 64 + lg * 16);
#pragma unroll
        for (int n = 0; n < 8; ++n) {
          bfrag vf = FRV(d, n * 16 + lc, k2 * 4 + lg);
          O[n] = MFMA16(pf, vf, O[n]);
        }
      }
      if (kt + 1 < nkv) asm volatile("s_waitcnt vmcnt(0)" ::: "memory");  // next tile landed
      asm volatile("s_waitcnt lgkmcnt(0)" ::: "memory");
      __builtin_amdgcn_s_barrier();
    }
#pragma unroll
    for (int n = 0; n < 8; ++n)
#pragma unroll
      for (int i = 0; i < 4; ++i)
        av[(size_t)(qr + lg * 4 + i) * 2048 + h * 128 + n * 16 + lc] = bf16_t(O[n][i] / lsum[i]);
    __builtin_amdgcn_s_barrier();  // all waves done before next half re-stages buf0
  }
#undef FRK
#undef FRV
}

extern "C" void kernel_launch(void* const* d_in, const int* in_sizes, int n_in,
                              void* d_out, int out_size, void* d_ws, size_t ws_size,
                              hipStream_t stream) {
  const float* x        = (const float*)d_in[0];
  const float* ln_scale = (const float*)d_in[1];
  const float* ln_offset= (const float*)d_in[2];
  const float* w_qkv    = (const float*)d_in[3];   // [2048][6144]
  const float* w_ao     = (const float*)d_in[4];   // [2048][2048]
  const float* w_ff_in  = (const float*)d_in[5];   // [2048][8192]
  const float* b_ff_in  = (const float*)d_in[6];   // [8192]
  const float* w_ff_out = (const float*)d_in[7];   // [8192][2048]
  const float* b_ff_out = (const float*)d_in[8];   // [2048]
  float* out = (float*)d_out;

  char* ws = (char*)d_ws;
  bf16_t* wqkvT   = (bf16_t*)(ws);                  // [6144][2048]  (dead after qkv GEMM)
  bf16_t* waoT    = (bf16_t*)(ws + 25165824);       // [2048][2048]
  bf16_t* wffinT  = (bf16_t*)(ws + 33554432);       // [8192][2048]
  bf16_t* wffoutT = (bf16_t*)(ws + 67108864);       // [2048][8192]
  bf16_t* h       = (bf16_t*)(ws + 100663296);      // [2048][2048]
  bf16_t* qhb     = (bf16_t*)(ws + 109051904);      // [16][2048][128]
  bf16_t* khb     = (bf16_t*)(ws + 117440512);
  bf16_t* vTb     = (bf16_t*)(ws + 125829120);      // [16][128][2048]
  bf16_t* avb     = (bf16_t*)(ws + 134217728);      // [2048][2048]
  bf16_t* qkvb    = (bf16_t*)(ws + 142606336);      // [2048][6144]; later ff1 [2048][8192]
  bf16_t* ff1b    = qkvb;
  float*  pa      = (float*)(ws + 142606336);       // attn_out partials (over dead qkvb)
  float*  pf      = (float*)(ws);                   // ff_out partials (over dead weights)

  hipFuncSetAttribute((const void*)gemm8p<0>,  hipFuncAttributeMaxDynamicSharedMemorySize, 131072);
  hipFuncSetAttribute((const void*)gemm8p<8>,  hipFuncAttributeMaxDynamicSharedMemorySize, 131072);
  hipFuncSetAttribute((const void*)gemm8p<11>, hipFuncAttributeMaxDynamicSharedMemorySize, 131072);

  dim3 b256(256), b512(512);
  transpose_cvt<<<dim3(192, 64),  b256, 0, stream>>>(w_qkv,    wqkvT,   2048, 6144);
  transpose_cvt<<<dim3(64, 64),   b256, 0, stream>>>(w_ao,     waoT,    2048, 2048);
  transpose_cvt<<<dim3(256, 64),  b256, 0, stream>>>(w_ff_in,  wffinT,  2048, 8192);
  transpose_cvt<<<dim3(64, 256),  b256, 0, stream>>>(w_ff_out, wffoutT, 8192, 2048);
  ln_kernel<<<dim3(2048), b256, 0, stream>>>(x, ln_scale, ln_offset, h);

  gemm8p<8><<<dim3(24, 8, 1), b512, 131072, stream>>>(h, 2048, wqkvT, 2048,
      nullptr, nullptr, qkvb, 2048, 6144, 2048, 0);
  rope_kernel<<<dim3(2048, 16), dim3(128), 0, stream>>>(qkvb, qhb, khb, vTb);
  attn_kernel<<<dim3(16, 16), b256, 0, stream>>>(qhb, khb, vTb, avb);

  // attn_out: split-K=2 (K=1024 each)
  gemm8p<0><<<dim3(8, 8, 2), b512, 131072, stream>>>(avb, 2048, waoT, 2048,
      nullptr, pa, nullptr, 2048, 2048, 1024, (size_t)2048 * 2048);
  reduceP<2, false, false><<<dim3(4096), b256, 0, stream>>>(pa, pa + 4194304,
      nullptr, nullptr, nullptr, out, 4194304, 2047);

  gemm8p<11><<<dim3(32, 8, 1), b512, 131072, stream>>>(h, 2048, wffinT, 2048,
      b_ff_in, nullptr, ff1b, 2048, 8192, 2048, 0);

  // ff_out: split-K=4 (K=2048 each)
  gemm8p<0><<<dim3(8, 8, 4), b512, 131072, stream>>>(ff1b, 8192, wffoutT, 8192,
      nullptr, pf, nullptr, 2048, 2048, 2048, (size_t)2048 * 2048);
  reduceP<4, true, true><<<dim3(4096), b256, 0, stream>>>(pf, pf + 4194304,
      pf + 2 * 4194304, pf + 3 * 4194304, b_ff_out, out, 4194304, 2047);
}